// Round 11
// baseline (318.280 us; speedup 1.0000x reference)
//
#include <hip/hip_runtime.h>

typedef float v2f __attribute__((ext_vector_type(2)));

// Structural constants (mirror reference)
#define NPOSE 64
#define NROT  128
#define NATOM 8
#define EPS   1e-2f

#define TS    16
#define NTILE (NROT / TS)
#define NPAIR (NTILE * (NTILE + 1) / 2)
#define CSTR  28
#define SSTR  17

#define UNRANK()                                            \
    const int bid = blockIdx.x;                             \
    const int p   = bid / NPAIR;                            \
    int t = bid - p * NPAIR;                                \
    int ti = 0;                                             \
    while (t >= NTILE - ti) { t -= NTILE - ti; ++ti; }      \
    const int tj = ti + t;

#define STAGE(OFF)                                                        \
    for (int idx = tid; idx < 2 * TS * 24; idx += 256) {                  \
        const int set = idx >= TS * 24;                                   \
        const int loc = idx - set * (TS * 24);                            \
        const int r   = loc / 24;                                         \
        const int k   = loc - r * 24;                                     \
        const float v = src[(set ? tj : ti) * (TS * 24) + loc + (OFF)];   \
        (set ? ldsJ : ldsI)[r * CSTR + k] = v;                            \
    }

#define EPILOGUE(DST)                                                      \
    res0[ty * SSTR + tx] = s0;                                             \
    res1[ty * SSTR + tx] = s1;                                             \
    const int nnz = NPOSE * NROT * NROT;                                   \
    const int gi  = ti * TS + ty;                                          \
    const int gj  = tj * TS + tx;                                          \
    const int n   = (p * NROT + gi) * NROT + gj;                           \
    DST[0 * nnz + n] = s0;                                                 \
    DST[1 * nnz + n] = s1;                                                 \
    DST[2 * nnz + n] = (float)p;                                           \
    DST[3 * nnz + n] = (float)(p * NROT + gi);                             \
    DST[4 * nnz + n] = (float)(p * NROT + gj);                             \
    if (ti != tj) {                                                        \
        __syncthreads();                                                   \
        const float m0 = res0[tx * SSTR + ty];                             \
        const float m1 = res1[tx * SSTR + ty];                             \
        const int mi = tj * TS + ty;                                       \
        const int mj = ti * TS + tx;                                       \
        const int nm = (p * NROT + mi) * NROT + mj;                        \
        DST[0 * nnz + nm] = m0;                                            \
        DST[1 * nnz + nm] = m1;                                            \
        DST[2 * nnz + nm] = (float)p;                                      \
        DST[3 * nnz + nm] = (float)(p * NROT + mi);                        \
        DST[4 * nnz + nm] = (float)(p * NROT + mj);                        \
    }

// ---------------- real kernel: R5 exact (19.06 us baseline) ----------------
__global__ __launch_bounds__(256, 4) void rot_score_kernel(
    const float* __restrict__ coords, float* __restrict__ out)
{
    __shared__ float ldsI[TS * CSTR];
    __shared__ float ldsJ[TS * CSTR];
    __shared__ float res0[TS * SSTR];
    __shared__ float res1[TS * SSTR];

    UNRANK();
    const int tid = threadIdx.x;
    const float* src = coords + (size_t)p * (NROT * NATOM * 3);
    STAGE(0);
    __syncthreads();

    const int ty = tid >> 4;
    const int tx = tid & 15;

    float4 xi4[6];
    {
        const float4* rowI = (const float4*)&ldsI[ty * CSTR];
#pragma unroll
        for (int k = 0; k < 6; ++k) xi4[k] = rowI[k];
    }
    float* xi = (float*)xi4;

    float sqi[NATOM];
#pragma unroll
    for (int a = 0; a < NATOM; ++a)
        sqi[a] = fmaf(xi[a*3+2], xi[a*3+2], fmaf(xi[a*3+1], xi[a*3+1], xi[a*3+0]*xi[a*3+0]));
#pragma unroll
    for (int k = 0; k < 24; ++k) xi[k] = xi[k] * -2.0f;

    const float SCH_S = -12102203.0f;
    const float SCH_B = 1064866805.0f;
    const v2f veps = { EPS, EPS };
    const float* rowJ = &ldsJ[tx * CSTR];

    v2f s0v = { 0.0f, 0.0f }, s1v = { 0.0f, 0.0f };

#pragma unroll
    for (int bp = 0; bp < 4; ++bp) {
        const float j0 = rowJ[bp*6 + 0];
        const float j1 = rowJ[bp*6 + 1];
        const float j2 = rowJ[bp*6 + 2];
        const float j3 = rowJ[bp*6 + 3];
        const float j4 = rowJ[bp*6 + 4];
        const float j5 = rowJ[bp*6 + 5];
        const v2f ax = { j0, j3 };
        const v2f ay = { j1, j4 };
        const v2f az = { j2, j5 };
        const v2f sj = __builtin_elementwise_fma(az, az,
                        __builtin_elementwise_fma(ay, ay, ax * ax));
#pragma unroll
        for (int a = 0; a < NATOM; ++a) {
            v2f t = sj + sqi[a];
            t = __builtin_elementwise_fma((v2f)(xi[a*3+0]), ax, t);
            t = __builtin_elementwise_fma((v2f)(xi[a*3+1]), ay, t);
            t = __builtin_elementwise_fma((v2f)(xi[a*3+2]), az, t);
            t = __builtin_elementwise_max(t, veps);
            const v2f rs = { __builtin_amdgcn_rsqf(t.x), __builtin_amdgcn_rsqf(t.y) };
            s0v = __builtin_elementwise_fma(rs, rs, s0v);
            const v2f dv = t * rs;
            const v2f st = __builtin_elementwise_fma(dv, (v2f)(SCH_S), (v2f)(SCH_B));
            v2f e;
            e.x = __int_as_float((int)st.x);
            e.y = __int_as_float((int)st.y);
            s1v += e;
        }
    }
    const float s0 = s0v.x + s0v.y;
    const float s1 = s1v.x + s1v.y;

    EPILOGUE(out);
}

// ---------------- V1: structure x64 (staging + barriers + LDS reads) ----------------
__global__ __launch_bounds__(256, 4) void ablate_structure(
    const float* __restrict__ coords, float* __restrict__ ws)
{
    __shared__ float ldsI[TS * CSTR];
    __shared__ float ldsJ[TS * CSTR];
    __shared__ float res0[TS * SSTR];
    __shared__ float res1[TS * SSTR];

    UNRANK();
    const int tid = threadIdx.x;
    const float* src = coords + (size_t)p * (NROT * NATOM * 3);
    const int ty = tid >> 4;
    const int tx = tid & 15;

    float acc = 0.0f;
#pragma unroll 1
    for (int rep = 0; rep < 64; ++rep) {
        int off = 0;
        asm volatile("" : "+v"(off));       // opaque 0: defeat hoisting of global loads
        STAGE(off);
        __syncthreads();
        float4 xi4[6];
        {
            const float4* rowI = (const float4*)&ldsI[ty * CSTR];
#pragma unroll
            for (int k = 0; k < 6; ++k) xi4[k] = rowI[k];
        }
        const float* xif = (const float*)xi4;
        const float* rowJ = &ldsJ[tx * CSTR];
        float s = 0.0f;
#pragma unroll
        for (int k = 0; k < 24; ++k) s += xif[k];
#pragma unroll
        for (int b = 0; b < 24; ++b) s += rowJ[b];
        acc += s;
        __syncthreads();
    }
    const float s0 = acc;
    const float s1 = acc * 0.5f;
    EPILOGUE(ws);
}

// ---------------- V2/V3: math loop repeated (trans on/off) ----------------
template <bool USE_TRANS, int REPS>
__global__ __launch_bounds__(256, 4) void ablate_math(
    const float* __restrict__ coords, float* __restrict__ ws)
{
    __shared__ float ldsI[TS * CSTR];
    __shared__ float ldsJ[TS * CSTR];
    __shared__ float res0[TS * SSTR];
    __shared__ float res1[TS * SSTR];

    UNRANK();
    const int tid = threadIdx.x;
    const float* src = coords + (size_t)p * (NROT * NATOM * 3);
    STAGE(0);
    __syncthreads();

    const int ty = tid >> 4;
    const int tx = tid & 15;

    float4 xi4[6];
    {
        const float4* rowI = (const float4*)&ldsI[ty * CSTR];
#pragma unroll
        for (int k = 0; k < 6; ++k) xi4[k] = rowI[k];
    }
    float* xi = (float*)xi4;

    float sqi[NATOM];
#pragma unroll
    for (int a = 0; a < NATOM; ++a)
        sqi[a] = fmaf(xi[a*3+2], xi[a*3+2], fmaf(xi[a*3+1], xi[a*3+1], xi[a*3+0]*xi[a*3+0]));
#pragma unroll
    for (int k = 0; k < 24; ++k) xi[k] = xi[k] * -2.0f;

    const float SCH_S = -12102203.0f;
    const float SCH_B = 1064866805.0f;
    const v2f veps = { EPS, EPS };

    v2f s0v = { 0.0f, 0.0f }, s1v = { 0.0f, 0.0f };

#pragma unroll 1
    for (int rep = 0; rep < REPS; ++rep) {
        float bias = 0.0f;
        int joff = 0;
        asm volatile("" : "+v"(bias), "+v"(joff));   // opaque: defeat cross-rep CSE
        const float* rowJ = &ldsJ[tx * CSTR] + joff;
#pragma unroll
        for (int bp = 0; bp < 4; ++bp) {
            const float j0 = rowJ[bp*6 + 0];
            const float j1 = rowJ[bp*6 + 1];
            const float j2 = rowJ[bp*6 + 2];
            const float j3 = rowJ[bp*6 + 3];
            const float j4 = rowJ[bp*6 + 4];
            const float j5 = rowJ[bp*6 + 5];
            const v2f ax = { j0, j3 };
            const v2f ay = { j1, j4 };
            const v2f az = { j2, j5 };
            v2f sj = __builtin_elementwise_fma(az, az,
                      __builtin_elementwise_fma(ay, ay, ax * ax));
            sj = sj + bias;                           // poison all downstream values
#pragma unroll
            for (int a = 0; a < NATOM; ++a) {
                v2f t = sj + sqi[a];
                t = __builtin_elementwise_fma((v2f)(xi[a*3+0]), ax, t);
                t = __builtin_elementwise_fma((v2f)(xi[a*3+1]), ay, t);
                t = __builtin_elementwise_fma((v2f)(xi[a*3+2]), az, t);
                t = __builtin_elementwise_max(t, veps);
                v2f rs;
                if (USE_TRANS) {
                    rs.x = __builtin_amdgcn_rsqf(t.x);
                    rs.y = __builtin_amdgcn_rsqf(t.y);
                } else {
                    rs = t * 0.0625f;                 // full-rate stand-in
                }
                s0v = __builtin_elementwise_fma(rs, rs, s0v);
                const v2f dv = t * rs;
                const v2f st = __builtin_elementwise_fma(dv, (v2f)(SCH_S), (v2f)(SCH_B));
                v2f e;
                e.x = __int_as_float((int)st.x);
                e.y = __int_as_float((int)st.y);
                s1v += e;
            }
        }
    }
    const float s0 = s0v.x + s0v.y;
    const float s1 = s1v.x + s1v.y;
    EPILOGUE(ws);
}

extern "C" void kernel_launch(void* const* d_in, const int* in_sizes, int n_in,
                              void* d_out, int out_size, void* d_ws, size_t ws_size,
                              hipStream_t stream) {
    (void)in_sizes; (void)n_in; (void)out_size;
    const float* coords = (const float*)d_in[0];
    float* out = (float*)d_out;

    dim3 grid(NPOSE * NPAIR);
    dim3 block(256);
    // Real kernel (unchanged R5): correctness + baseline.
    rot_score_kernel<<<grid, block, 0, stream>>>(coords, out);

    // MEASUREMENT ROUND: phase-ablation kernels into d_ws (visible in top-5 counters).
    const size_t REGION = 8u * 1024u * 1024u;   // floats (32 MB each)
    if (ws_size >= 3u * REGION * sizeof(float)) {
        float* w = (float*)d_ws;
        ablate_structure<<<grid, block, 0, stream>>>(coords, w);
        ablate_math<false, 16><<<grid, block, 0, stream>>>(coords, w + REGION);
        ablate_math<true,   8><<<grid, block, 0, stream>>>(coords, w + 2 * REGION);
    }
}

// Round 12
// 20.803 us; speedup vs baseline: 15.2999x; 15.2999x over previous
//
#include <hip/hip_runtime.h>

// Structural constants (mirror reference)
#define NPOSE 64
#define NROT  128
#define NATOM 8
#define EPS   1e-2f

#define TS    16                 // rotamer tile size
#define NTILE (NROT / TS)        // 8 tiles per axis
#define NPAIR (NTILE * (NTILE + 1) / 2)   // 36 tile pairs (ti <= tj)
#define CSTR  28                 // coord LDS row stride: 24 + 4 pad -> 112B, 16B-aligned rows
#define SSTR  17                 // result tile row stride (16 + 1 pad)

// Scalar-minimal inner loop; lean live set -> natural VGPR <= 64 -> 8 waves/SIMD.
__global__ __launch_bounds__(256, 4) void rot_score_kernel(
    const float* __restrict__ coords,
    float* __restrict__ out)
{
    __shared__ float ldsI[TS * CSTR];
    __shared__ float ldsJ[TS * CSTR];
    __shared__ float res0[TS * SSTR];
    __shared__ float res1[TS * SSTR];

    const int bid = blockIdx.x;
    const int p   = bid / NPAIR;
    int t = bid - p * NPAIR;
    int ti = 0;
    while (t >= NTILE - ti) { t -= NTILE - ti; ++ti; }   // unrank upper triangle
    const int tj = ti + t;

    const int tid = threadIdx.x;
    const float* src = coords + (size_t)p * (NROT * NATOM * 3);

    // Stage the two 16-rotamer coordinate sets (16 x 24 floats each), coalesced reads.
    for (int idx = tid; idx < 2 * TS * 24; idx += 256) {
        const int set = idx >= TS * 24;
        const int loc = idx - set * (TS * 24);
        const int r   = loc / 24;
        const int k   = loc - r * 24;
        const float v = src[(set ? tj : ti) * (TS * 24) + loc];
        (set ? ldsJ : ldsI)[r * CSTR + k] = v;
    }
    __syncthreads();

    const int ty = tid >> 4;    // i within tile (0..15)
    const int tx = tid & 15;    // j within tile (0..15)

    // i-rotamer fully in registers (broadcast reads, 6x ds_read_b128).
    float4 xi4[6];
    {
        const float4* rowI = (const float4*)&ldsI[ty * CSTR];
#pragma unroll
        for (int k = 0; k < 6; ++k) xi4[k] = rowI[k];
    }
    float* xi = (float*)xi4;

    // Per-atom squared norms; pre-scale xi by -2 so d2 = (sqi+sqj) + sum(xi2*xj).
    float sqi[NATOM];
#pragma unroll
    for (int a = 0; a < NATOM; ++a)
        sqi[a] = fmaf(xi[a*3+2], xi[a*3+2], fmaf(xi[a*3+1], xi[a*3+1], xi[a*3+0]*xi[a*3+0]));
#pragma unroll
    for (int k = 0; k < 24; ++k) xi[k] = xi[k] * -2.0f;

    const float SCH_S = -12102203.0f;   // -(2^23)/ln2  (Schraudolph exp)
    const float SCH_B = 1064866805.0f;  // bias
    const float* rowJ = &ldsJ[tx * CSTR];

    float s0 = 0.0f, s1 = 0.0f;

    // b-loop NOT unrolled: j-atom floats streamed from LDS stay 3-deep, never
    // hoisted into 24 live registers. a-loop fully unrolled: 8 independent
    // 11-op chains per iteration for ILP.
#pragma unroll 1
    for (int b = 0; b < NATOM; ++b) {
        const float jx = rowJ[b*3 + 0];
        const float jy = rowJ[b*3 + 1];
        const float jz = rowJ[b*3 + 2];
        const float sqj = fmaf(jz, jz, fmaf(jy, jy, jx * jx));
#pragma unroll
        for (int a = 0; a < NATOM; ++a) {
            float d2 = sqi[a] + sqj;             // v_add_f32
            d2 = fmaf(xi[a*3+0], jx, d2);        // 3x v_fmac_f32 (xi pre-scaled -2)
            d2 = fmaf(xi[a*3+1], jy, d2);
            d2 = fmaf(xi[a*3+2], jz, d2);
            d2 = fmaxf(d2, EPS);                 // v_max_f32
            const float rs = __builtin_amdgcn_rsqf(d2);   // v_rsq_f32
            s0 = fmaf(rs, rs, s0);               // v_fmac_f32 : += 1/d2
            const float d  = d2 * rs;            // v_mul_f32  : sqrt(d2)
            const float st = fmaf(d, SCH_S, SCH_B);       // v_fma_f32
            s1 += __int_as_float((int)st);       // v_cvt_i32_f32 + v_add_f32
        }
    }

    // Stage results for the coalesced mirror write.
    res0[ty * SSTR + tx] = s0;
    res1[ty * SSTR + tx] = s1;

    const int nnz = NPOSE * NROT * NROT;
    const int gi  = ti * TS + ty;
    const int gj  = tj * TS + tx;
    const int n   = (p * NROT + gi) * NROT + gj;

    out[0 * nnz + n] = s0;
    out[1 * nnz + n] = s1;
    out[2 * nnz + n] = (float)p;
    out[3 * nnz + n] = (float)(p * NROT + gi);
    out[4 * nnz + n] = (float)(p * NROT + gj);

    if (ti != tj) {              // block-uniform branch
        __syncthreads();
        const float m0 = res0[tx * SSTR + ty];   // value of pair (ti*TS+tx, tj*TS+ty)
        const float m1 = res1[tx * SSTR + ty];
        const int mi = tj * TS + ty;
        const int mj = ti * TS + tx;
        const int nm = (p * NROT + mi) * NROT + mj;
        out[0 * nnz + nm] = m0;
        out[1 * nnz + nm] = m1;
        out[2 * nnz + nm] = (float)p;
        out[3 * nnz + nm] = (float)(p * NROT + mi);
        out[4 * nnz + nm] = (float)(p * NROT + mj);
    }
}

extern "C" void kernel_launch(void* const* d_in, const int* in_sizes, int n_in,
                              void* d_out, int out_size, void* d_ws, size_t ws_size,
                              hipStream_t stream) {
    (void)in_sizes; (void)n_in; (void)d_ws; (void)ws_size; (void)out_size;
    const float* coords = (const float*)d_in[0];
    float* out = (float*)d_out;

    dim3 grid(NPOSE * NPAIR);   // 64 poses x 36 upper-triangle tile pairs = 2304 blocks
    dim3 block(256);
    rot_score_kernel<<<grid, block, 0, stream>>>(coords, out);
}

// Round 13
// 20.671 us; speedup vs baseline: 15.3973x; 1.0064x over previous
//
#include <hip/hip_runtime.h>

// Structural constants (mirror reference)
#define NPOSE 64
#define NROT  128
#define NATOM 8
#define EPS   1e-2f

#define TS    16                 // rotamer tile size
#define NTILE (NROT / TS)        // 8 tiles per axis
#define NPAIR (NTILE * (NTILE + 1) / 2)   // 36 tile pairs (ti <= tj)
#define CSTR  28                 // coord LDS row stride: 24 + 4 pad -> 112B, 16B-aligned rows
#define SSTR  17                 // result tile row stride (16 + 1 pad)

// Zero-transcendental inner loop: rcp via magic+Newton, exp(-sqrt) via
// sqrt-magic + Schraudolph. 14 full-rate VALU instr / eval.
__global__ __launch_bounds__(256, 4) void rot_score_kernel(
    const float* __restrict__ coords,
    float* __restrict__ out)
{
    __shared__ float ldsI[TS * CSTR];
    __shared__ float ldsJ[TS * CSTR];
    __shared__ float res0[TS * SSTR];
    __shared__ float res1[TS * SSTR];

    const int bid = blockIdx.x;
    const int p   = bid / NPAIR;
    int t = bid - p * NPAIR;
    int ti = 0;
    while (t >= NTILE - ti) { t -= NTILE - ti; ++ti; }   // unrank upper triangle
    const int tj = ti + t;

    const int tid = threadIdx.x;
    const float* src = coords + (size_t)p * (NROT * NATOM * 3);

    // Stage the two 16-rotamer coordinate sets (16 x 24 floats each), coalesced reads.
    for (int idx = tid; idx < 2 * TS * 24; idx += 256) {
        const int set = idx >= TS * 24;
        const int loc = idx - set * (TS * 24);
        const int r   = loc / 24;
        const int k   = loc - r * 24;
        const float v = src[(set ? tj : ti) * (TS * 24) + loc];
        (set ? ldsJ : ldsI)[r * CSTR + k] = v;
    }
    __syncthreads();

    const int ty = tid >> 4;    // i within tile (0..15)
    const int tx = tid & 15;    // j within tile (0..15)

    // i-rotamer fully in registers (broadcast reads, 6x ds_read_b128).
    float4 xi4[6];
    {
        const float4* rowI = (const float4*)&ldsI[ty * CSTR];
#pragma unroll
        for (int k = 0; k < 6; ++k) xi4[k] = rowI[k];
    }
    float* xi = (float*)xi4;

    // Per-atom squared norms; pre-scale xi by -2 so d2 = (sqi+sqj) + sum(xi2*xj).
    float sqi[NATOM];
#pragma unroll
    for (int a = 0; a < NATOM; ++a)
        sqi[a] = fmaf(xi[a*3+2], xi[a*3+2], fmaf(xi[a*3+1], xi[a*3+1], xi[a*3+0]*xi[a*3+0]));
#pragma unroll
    for (int k = 0; k < 24; ++k) xi[k] = xi[k] * -2.0f;

    const float SCH_S = -12102203.0f;   // -(2^23)/ln2  (Schraudolph exp)
    const float SCH_B = 1064866805.0f;  // bias
    const float* rowJ = &ldsJ[tx * CSTR];

    float s0 = 0.0f, s1 = 0.0f;

    // b-loop NOT unrolled (low register pressure); a-loop fully unrolled
    // (8 independent 14-op full-rate chains, no trans-pipe ops at all).
#pragma unroll 1
    for (int b = 0; b < NATOM; ++b) {
        const float jx = rowJ[b*3 + 0];
        const float jy = rowJ[b*3 + 1];
        const float jz = rowJ[b*3 + 2];
        const float sqj = fmaf(jz, jz, fmaf(jy, jy, jx * jx));
#pragma unroll
        for (int a = 0; a < NATOM; ++a) {
            float d2 = sqi[a] + sqj;             // v_add_f32
            d2 = fmaf(xi[a*3+0], jx, d2);        // 3x v_fmac_f32 (xi pre-scaled -2)
            d2 = fmaf(xi[a*3+1], jy, d2);
            d2 = fmaf(xi[a*3+2], jz, d2);
            d2 = fmaxf(d2, EPS);                 // v_max_f32

            const int ib = __float_as_int(d2);

            // s0: 1/d2 via reciprocal magic + one Newton step (max rel err ~0.1%)
            const float r0 = __int_as_float(0x7EF311C3 - ib);   // v_sub_u32
            const float r  = r0 * fmaf(-d2, r0, 2.0f);          // v_fma + v_mul
            s0 += r;                                            // v_add_f32

            // s1: exp(-sqrt(d2)) via sqrt magic + Schraudolph (term err ~<0.04)
            const float sq = __int_as_float((ib >> 1) + 0x1FBD1DF5); // v_ashr + v_add_u32
            const float st = fmaf(sq, SCH_S, SCH_B);            // v_fma_f32
            s1 += __int_as_float((int)st);                      // v_cvt_i32 + v_add_f32
        }
    }

    // Stage results for the coalesced mirror write.
    res0[ty * SSTR + tx] = s0;
    res1[ty * SSTR + tx] = s1;

    const int nnz = NPOSE * NROT * NROT;
    const int gi  = ti * TS + ty;
    const int gj  = tj * TS + tx;
    const int n   = (p * NROT + gi) * NROT + gj;

    out[0 * nnz + n] = s0;
    out[1 * nnz + n] = s1;
    out[2 * nnz + n] = (float)p;
    out[3 * nnz + n] = (float)(p * NROT + gi);
    out[4 * nnz + n] = (float)(p * NROT + gj);

    if (ti != tj) {              // block-uniform branch
        __syncthreads();
        const float m0 = res0[tx * SSTR + ty];   // value of pair (ti*TS+tx, tj*TS+ty)
        const float m1 = res1[tx * SSTR + ty];
        const int mi = tj * TS + ty;
        const int mj = ti * TS + tx;
        const int nm = (p * NROT + mi) * NROT + mj;
        out[0 * nnz + nm] = m0;
        out[1 * nnz + nm] = m1;
        out[2 * nnz + nm] = (float)p;
        out[3 * nnz + nm] = (float)(p * NROT + mi);
        out[4 * nnz + nm] = (float)(p * NROT + mj);
    }
}

extern "C" void kernel_launch(void* const* d_in, const int* in_sizes, int n_in,
                              void* d_out, int out_size, void* d_ws, size_t ws_size,
                              hipStream_t stream) {
    (void)in_sizes; (void)n_in; (void)d_ws; (void)ws_size; (void)out_size;
    const float* coords = (const float*)d_in[0];
    float* out = (float*)d_out;

    dim3 grid(NPOSE * NPAIR);   // 64 poses x 36 upper-triangle tile pairs = 2304 blocks
    dim3 block(256);
    rot_score_kernel<<<grid, block, 0, stream>>>(coords, out);
}